// Round 1
// baseline (111.948 us; speedup 1.0000x reference)
//
#include <hip/hip_runtime.h>

#define NUM_LAYERS 32
#define HIDDEN 2048
#define RANK 64
#define BATCH 2048
#define KC 128               // h-chunk (K) per k_proj block
#define HCH 128              // h-chunk (N) per k_delta block
#define MB_P 64              // samples per pass, k_proj
#define MB_D 128             // samples per pass, k_delta
#define ZPAD 136             // ushort row stride, z tile (16B-aligned, 4-bank shift)
#define VPAD 136             // ushort row stride, v tile
#define UPAD 72              // ushort row stride, u tile
#define PPAD 72              // ushort row stride, p tile

typedef __attribute__((ext_vector_type(8))) short bf16x8;
typedef __attribute__((ext_vector_type(4))) float f32x4;

static __device__ __forceinline__ ushort f2bf(float x) {
    unsigned b = __builtin_bit_cast(unsigned, x);
    b += 0x7fffu + ((b >> 16) & 1u);          // round-to-nearest-even
    return (ushort)(b >> 16);
}
static __device__ __forceinline__ ushort4 pack4(float4 v) {
    ushort4 r; r.x = f2bf(v.x); r.y = f2bf(v.y); r.z = f2bf(v.z); r.w = f2bf(v.w);
    return r;
}

// Workspace: proj [BATCH][RANK] f32 (zeroed), counts[32], offsets[32], perm[BATCH]
__global__ __launch_bounds__(256)
void k_bucket(const int* __restrict__ ids, float* __restrict__ proj,
              int* __restrict__ counts, int* __restrict__ offsets,
              int* __restrict__ perm)
{
    if (blockIdx.x == 0) {
        __shared__ int cnt[NUM_LAYERS];
        __shared__ int off[NUM_LAYERS];
        __shared__ int cur[NUM_LAYERS];
        const int t = threadIdx.x;
        if (t < NUM_LAYERS) cnt[t] = 0;
        __syncthreads();
        for (int i = t; i < BATCH; i += 256) atomicAdd(&cnt[ids[i]], 1);
        __syncthreads();
        if (t == 0) {
            int a = 0;
            for (int l = 0; l < NUM_LAYERS; ++l) { off[l] = a; a += cnt[l]; }
        }
        __syncthreads();
        if (t < NUM_LAYERS) { cur[t] = 0; counts[t] = cnt[t]; offsets[t] = off[t]; }
        __syncthreads();
        for (int i = t; i < BATCH; i += 256) {
            int l = ids[i];
            int p = off[l] + atomicAdd(&cur[l], 1);
            perm[p] = i;
        }
    } else {
        const int b = blockIdx.x - 1;          // 8 zero blocks
        float4* p4 = (float4*)proj;
        const int per = BATCH * RANK / 4 / 8;  // 4096 float4 each
        for (int i = threadIdx.x; i < per; i += 256)
            p4[b * per + i] = make_float4(0.f, 0.f, 0.f, 0.f);
    }
}

// K1: proj[b,r] += sum_{h in chunk} z[b,h] * v[l,h,r]   via MFMA bf16
// 512 threads: wave w -> r-tile (w&3), sample-half (w>>2). 64 samples/pass.
// All loads issued ahead of first use; z tile double-buffered, 1 sync/pass.
__global__ __launch_bounds__(512)
void k_proj(const float* __restrict__ z, const float* __restrict__ v,
            const int* __restrict__ counts, const int* __restrict__ offsets,
            const int* __restrict__ perm, float* __restrict__ proj)
{
    const int kc = blockIdx.x, l = blockIdx.y;
    const int n = counts[l];
    if (n == 0) return;
    const int o = offsets[l];
    const int t = threadIdx.x;
    const int w = t >> 6, lane = t & 63;
    const int m16 = lane & 15, quad = lane >> 4;
    const int wr = w & 3, wm = w >> 2;
    const int kbase = kc * KC;

    __shared__ int    bidx[BATCH];           // 8 KB (worst case all one layer)
    __shared__ ushort vt[RANK * VPAD];       // 17 KB  [r][h] transposed
    __shared__ ushort zt[2][MB_P * ZPAD];    // 34 KB  [si][h] double-buffered

    // stage perm -> LDS (small, issued first), then V loads (in flight to sync)
    for (int i = t; i < n; i += 512) bidx[i] = perm[o + i];
    float4 vreg[4];
    #pragma unroll
    for (int it = 0; it < 4; ++it) {
        const int idx = it * 512 + t;        // 2048 float4 = 128h x 16
        const int hh = idx >> 4, rq = idx & 15;
        vreg[it] = *(const float4*)&v[((size_t)l * HIDDEN + kbase + hh) * RANK + rq * 4];
    }
    __syncthreads();                         // bidx visible

    const int P = (n + MB_P - 1) / MB_P;
    // issue pass-0 z loads (overlap with V convert below)
    float4 zreg[4];
    {
        const int nb = (n < MB_P) ? n : MB_P;
        #pragma unroll
        for (int it = 0; it < 4; ++it) {
            const int idx = it * 512 + t;    // 2048 float4 = 64si x 32
            const int si = idx >> 5, q = idx & 31;
            zreg[it] = make_float4(0.f, 0.f, 0.f, 0.f);
            if (si < nb)
                zreg[it] = *(const float4*)&z[(size_t)bidx[si] * HIDDEN + kbase + q * 4];
        }
    }
    // convert + write V tile (transposed) while z loads fly
    #pragma unroll
    for (int it = 0; it < 4; ++it) {
        const int idx = it * 512 + t;
        const int hh = idx >> 4, rq = idx & 15;
        vt[(rq * 4 + 0) * VPAD + hh] = f2bf(vreg[it].x);
        vt[(rq * 4 + 1) * VPAD + hh] = f2bf(vreg[it].y);
        vt[(rq * 4 + 2) * VPAD + hh] = f2bf(vreg[it].z);
        vt[(rq * 4 + 3) * VPAD + hh] = f2bf(vreg[it].w);
    }

    for (int p = 0; p < P; ++p) {
        const int nbr = n - p * MB_P;
        const int nb = (nbr < MB_P) ? nbr : MB_P;
        #pragma unroll
        for (int it = 0; it < 4; ++it) {
            const int idx = it * 512 + t;
            const int si = idx >> 5, q = idx & 31;
            *(ushort4*)&zt[p & 1][si * ZPAD + q * 4] = pack4(zreg[it]);
        }
        __syncthreads();                     // vt (p==0) + zt[p&1] visible
        if (p + 1 < P) {                     // prefetch next pass into other buffer
            const int b2 = (p + 1) * MB_P;
            const int nb2r = n - b2;
            const int nb2 = (nb2r < MB_P) ? nb2r : MB_P;
            #pragma unroll
            for (int it = 0; it < 4; ++it) {
                const int idx = it * 512 + t;
                const int si = idx >> 5, q = idx & 31;
                zreg[it] = make_float4(0.f, 0.f, 0.f, 0.f);
                if (si < nb2)
                    zreg[it] = *(const float4*)&z[(size_t)bidx[b2 + si] * HIDDEN + kbase + q * 4];
            }
        }
        f32x4 acc0 = {0.f, 0.f, 0.f, 0.f}, acc1 = {0.f, 0.f, 0.f, 0.f};
        const ushort* zr0 = &zt[p & 1][(wm * 32 + m16) * ZPAD];
        const ushort* zr1 = zr0 + 16 * ZPAD;
        const ushort* vr  = &vt[(wr * 16 + m16) * VPAD];
        #pragma unroll
        for (int kt = 0; kt < 4; ++kt) {
            const int koff = kt * 32 + quad * 8;
            const bf16x8 bf = *(const bf16x8*)&vr[koff];
            const bf16x8 a0 = *(const bf16x8*)&zr0[koff];
            const bf16x8 a1 = *(const bf16x8*)&zr1[koff];
            acc0 = __builtin_amdgcn_mfma_f32_16x16x32_bf16(a0, bf, acc0, 0, 0, 0);
            acc1 = __builtin_amdgcn_mfma_f32_16x16x32_bf16(a1, bf, acc1, 0, 0, 0);
        }
        // C/D: col(=r)=lane&15, row(=si)=quad*4+reg ; fire-and-forget atomics
        const int r = wr * 16 + m16;
        const int base = p * MB_P;
        #pragma unroll
        for (int reg = 0; reg < 4; ++reg) {
            const int row = wm * 32 + quad * 4 + reg;
            if (row < nb)
                atomicAdd(&proj[(size_t)bidx[base + row] * RANK + r], acc0[reg]);
            if (row + 16 < nb)
                atomicAdd(&proj[(size_t)bidx[base + row + 16] * RANK + r], acc1[reg]);
        }
    }
}

// K2: out[b,h] = z[b,h] + sum_r proj[b,r] * u[l,h,r]   via MFMA bf16
// 512 threads: wave w -> h-tile (w&1, 64h), sample-group (w>>1, 32 samples).
// 128 samples/pass (P==1 for virtually all layers). proj + z-epilogue loads
// issued at block start; proj tile double-buffered.
__global__ __launch_bounds__(512)
void k_delta(const float* __restrict__ z, const float* __restrict__ u,
             const int* __restrict__ counts, const int* __restrict__ offsets,
             const int* __restrict__ perm, const float* __restrict__ proj,
             float* __restrict__ out)
{
    const int hc = blockIdx.x, l = blockIdx.y;
    const int n = counts[l];
    if (n == 0) return;
    const int o = offsets[l];
    const int t = threadIdx.x;
    const int w = t >> 6, lane = t & 63;
    const int m16 = lane & 15, quad = lane >> 4;
    const int wr = w & 1, wm = w >> 1;
    const int hbase = hc * HCH;

    __shared__ int    bidx[BATCH];           // 8 KB
    __shared__ ushort ut[HCH * UPAD];        // 18 KB [h][r]
    __shared__ ushort pt[2][MB_D * PPAD];    // 36 KB [si][r] double-buffered

    for (int i = t; i < n; i += 512) bidx[i] = perm[o + i];
    float4 ureg[4];
    #pragma unroll
    for (int it = 0; it < 4; ++it) {
        const int idx = it * 512 + t;        // 2048 float4 = 128h x 16
        const int hh = idx >> 4, rq = idx & 15;
        ureg[it] = *(const float4*)&u[((size_t)l * HIDDEN + hbase + hh) * RANK + rq * 4];
    }
    __syncthreads();                         // bidx visible

    const int P = (n + MB_D - 1) / MB_D;
    float4 preg[4];
    float  zep[2][4][4];
    {
        const int nb = (n < MB_D) ? n : MB_D;
        #pragma unroll
        for (int it = 0; it < 4; ++it) {     // 2048 float4 = 128si x 16
            const int idx = it * 512 + t;
            const int si = idx >> 4, rq = idx & 15;
            preg[it] = make_float4(0.f, 0.f, 0.f, 0.f);
            if (si < nb)
                preg[it] = *(const float4*)&proj[(size_t)bidx[si] * RANK + rq * 4];
        }
        #pragma unroll
        for (int mt = 0; mt < 2; ++mt)
            #pragma unroll
            for (int reg = 0; reg < 4; ++reg) {
                const int si = wm * 32 + mt * 16 + quad * 4 + reg;
                const size_t rowb = (si < nb) ? ((size_t)bidx[si] * HIDDEN + hbase) : 0;
                #pragma unroll
                for (int nt = 0; nt < 4; ++nt) {
                    const int h = (wr * 4 + nt) * 16 + m16;
                    zep[mt][nt][reg] = (si < nb) ? z[rowb + h] : 0.f;
                }
            }
    }
    // convert + write U tile while proj/z loads fly
    #pragma unroll
    for (int it = 0; it < 4; ++it) {
        const int idx = it * 512 + t;
        const int hh = idx >> 4, rq = idx & 15;
        *(ushort4*)&ut[hh * UPAD + rq * 4] = pack4(ureg[it]);
    }

    for (int p = 0; p < P; ++p) {
        const int nbr = n - p * MB_D;
        const int nb = (nbr < MB_D) ? nbr : MB_D;
        const int base = p * MB_D;
        #pragma unroll
        for (int it = 0; it < 4; ++it) {
            const int idx = it * 512 + t;
            const int si = idx >> 4, rq = idx & 15;
            *(ushort4*)&pt[p & 1][si * PPAD + rq * 4] = pack4(preg[it]);
        }
        __syncthreads();                     // ut (p==0) + pt[p&1] visible

        f32x4 acc[2][4];
        #pragma unroll
        for (int mt = 0; mt < 2; ++mt)
            #pragma unroll
            for (int nt = 0; nt < 4; ++nt)
                acc[mt][nt] = (f32x4){0.f, 0.f, 0.f, 0.f};

        const ushort* pr0 = &pt[p & 1][(wm * 32 + m16) * PPAD];
        const ushort* pr1 = pr0 + 16 * PPAD;
        #pragma unroll
        for (int kt = 0; kt < 2; ++kt) {
            const int koff = kt * 32 + quad * 8;
            const bf16x8 a0 = *(const bf16x8*)&pr0[koff];
            const bf16x8 a1 = *(const bf16x8*)&pr1[koff];
            #pragma unroll
            for (int nt = 0; nt < 4; ++nt) {
                const int h = (wr * 4 + nt) * 16 + m16;
                const bf16x8 bf = *(const bf16x8*)&ut[h * UPAD + koff];
                acc[0][nt] = __builtin_amdgcn_mfma_f32_16x16x32_bf16(a0, bf, acc[0][nt], 0, 0, 0);
                acc[1][nt] = __builtin_amdgcn_mfma_f32_16x16x32_bf16(a1, bf, acc[1][nt], 0, 0, 0);
            }
        }
        // epilogue: out = z + delta (z prefetched at block start / prev pass)
        #pragma unroll
        for (int mt = 0; mt < 2; ++mt)
            #pragma unroll
            for (int reg = 0; reg < 4; ++reg) {
                const int si = wm * 32 + mt * 16 + quad * 4 + reg;
                if (si < nb) {
                    const size_t rowb = (size_t)bidx[base + si] * HIDDEN + hbase;
                    #pragma unroll
                    for (int nt = 0; nt < 4; ++nt) {
                        const int h = (wr * 4 + nt) * 16 + m16;
                        out[rowb + h] = zep[mt][nt][reg] + acc[mt][nt][reg];
                    }
                }
            }
        // prefetch next pass (rare: only layers with n > 128)
        if (p + 1 < P) {
            const int b2 = (p + 1) * MB_D;
            const int nb2r = n - b2;
            const int nb2 = (nb2r < MB_D) ? nb2r : MB_D;
            #pragma unroll
            for (int it = 0; it < 4; ++it) {
                const int idx = it * 512 + t;
                const int si = idx >> 4, rq = idx & 15;
                preg[it] = make_float4(0.f, 0.f, 0.f, 0.f);
                if (si < nb2)
                    preg[it] = *(const float4*)&proj[(size_t)bidx[b2 + si] * RANK + rq * 4];
            }
            #pragma unroll
            for (int mt = 0; mt < 2; ++mt)
                #pragma unroll
                for (int reg = 0; reg < 4; ++reg) {
                    const int si = wm * 32 + mt * 16 + quad * 4 + reg;
                    const size_t rowb = (si < nb2) ? ((size_t)bidx[b2 + si] * HIDDEN + hbase) : 0;
                    #pragma unroll
                    for (int nt = 0; nt < 4; ++nt) {
                        const int h = (wr * 4 + nt) * 16 + m16;
                        zep[mt][nt][reg] = (si < nb2) ? z[rowb + h] : 0.f;
                    }
                }
        }
    }
}

extern "C" void kernel_launch(void* const* d_in, const int* in_sizes, int n_in,
                              void* d_out, int out_size, void* d_ws, size_t ws_size,
                              hipStream_t stream)
{
    const float* z   = (const float*)d_in[0];
    const int*   ids = (const int*)d_in[1];
    const float* u   = (const float*)d_in[2];
    const float* v   = (const float*)d_in[3];
    float* out = (float*)d_out;

    float* proj   = (float*)d_ws;                          // 512 KB
    int* counts   = (int*)(proj + (size_t)BATCH * RANK);
    int* offsets  = counts + NUM_LAYERS;
    int* perm     = offsets + NUM_LAYERS;

    hipLaunchKernelGGL(k_bucket, dim3(9), dim3(256), 0, stream,
                       ids, proj, counts, offsets, perm);
    hipLaunchKernelGGL(k_proj, dim3(HIDDEN / KC, NUM_LAYERS), dim3(512), 0, stream,
                       z, v, counts, offsets, perm, proj);
    hipLaunchKernelGGL(k_delta, dim3(HIDDEN / HCH, NUM_LAYERS), dim3(512), 0, stream,
                       z, u, counts, offsets, perm, proj, out);
}

// Round 2
// 108.930 us; speedup vs baseline: 1.0277x; 1.0277x over previous
//
#include <hip/hip_runtime.h>

#define NUM_LAYERS 32
#define HIDDEN 2048
#define RANK 64
#define BATCH 2048
#define KC 128               // h-chunk (K) per k_proj block
#define HCH 128              // h-chunk (N) per k_delta block
#define MB_P 64              // samples per pass, k_proj
#define MB_D 128             // samples per pass, k_delta
#define ZPAD 136             // ushort row stride, z tile (16B-aligned, 4-bank shift)
#define VPAD 136             // ushort row stride, v tile
#define UPAD 72              // ushort row stride, u tile
#define PPAD 72              // ushort row stride, p tile

typedef __attribute__((ext_vector_type(8))) short bf16x8;
typedef __attribute__((ext_vector_type(4))) float f32x4;

static __device__ __forceinline__ ushort f2bf(float x) {
    unsigned b = __builtin_bit_cast(unsigned, x);
    b += 0x7fffu + ((b >> 16) & 1u);          // round-to-nearest-even
    return (ushort)(b >> 16);
}
static __device__ __forceinline__ ushort4 pack4(float4 v) {
    ushort4 r; r.x = f2bf(v.x); r.y = f2bf(v.y); r.z = f2bf(v.z); r.w = f2bf(v.w);
    return r;
}

// K1: proj[b,r] += sum_{h in chunk} z[b,h] * v[l,h,r]   via MFMA bf16
// Self-derived sample list: each block scans ids (one int4/thread, L2-hot)
// and compacts matches into LDS. No bucket kernel, no perm buffer.
// 512 threads: wave w -> r-tile (w&3), sample-half (w>>2). 64 samples/pass.
__global__ __launch_bounds__(512)
void k_proj(const float* __restrict__ z, const float* __restrict__ v,
            const int* __restrict__ ids, float* __restrict__ proj)
{
    const int kc = blockIdx.x, l = blockIdx.y;
    const int t = threadIdx.x;
    const int w = t >> 6, lane = t & 63;
    const int m16 = lane & 15, quad = lane >> 4;
    const int wr = w & 3, wm = w >> 2;
    const int kbase = kc * KC;

    __shared__ int    lidx[BATCH];           // 8 KB (worst case all one layer)
    __shared__ int    nsh;
    __shared__ ushort vt[RANK * VPAD];       // 17 KB  [r][h] transposed
    __shared__ ushort zt[2][MB_P * ZPAD];    // 34 KB  [si][h] double-buffered

    if (t == 0) nsh = 0;

    // issue V loads first; they fly over the ids-scan/compaction
    float4 vreg[4];
    #pragma unroll
    for (int it = 0; it < 4; ++it) {
        const int idx = it * 512 + t;        // 2048 float4 = 128h x 16
        const int hh = idx >> 4, rq = idx & 15;
        vreg[it] = *(const float4*)&v[((size_t)l * HIDDEN + kbase + hh) * RANK + rq * 4];
    }
    __syncthreads();                         // nsh = 0 visible

    {
        const int4 iv = ((const int4*)ids)[t];   // 512 int4 = all 2048 ids
        if (iv.x == l) lidx[atomicAdd(&nsh, 1)] = t * 4 + 0;
        if (iv.y == l) lidx[atomicAdd(&nsh, 1)] = t * 4 + 1;
        if (iv.z == l) lidx[atomicAdd(&nsh, 1)] = t * 4 + 2;
        if (iv.w == l) lidx[atomicAdd(&nsh, 1)] = t * 4 + 3;
    }
    __syncthreads();                         // lidx, nsh final
    const int n = nsh;
    if (n == 0) return;

    const int P = (n + MB_P - 1) / MB_P;
    // issue pass-0 z gathers (overlap with V convert below)
    float4 zreg[4];
    {
        const int nb = (n < MB_P) ? n : MB_P;
        #pragma unroll
        for (int it = 0; it < 4; ++it) {
            const int idx = it * 512 + t;    // 2048 float4 = 64si x 32
            const int si = idx >> 5, q = idx & 31;
            zreg[it] = make_float4(0.f, 0.f, 0.f, 0.f);
            if (si < nb)
                zreg[it] = *(const float4*)&z[(size_t)lidx[si] * HIDDEN + kbase + q * 4];
        }
    }
    // convert + write V tile (transposed) while z loads fly
    #pragma unroll
    for (int it = 0; it < 4; ++it) {
        const int idx = it * 512 + t;
        const int hh = idx >> 4, rq = idx & 15;
        vt[(rq * 4 + 0) * VPAD + hh] = f2bf(vreg[it].x);
        vt[(rq * 4 + 1) * VPAD + hh] = f2bf(vreg[it].y);
        vt[(rq * 4 + 2) * VPAD + hh] = f2bf(vreg[it].z);
        vt[(rq * 4 + 3) * VPAD + hh] = f2bf(vreg[it].w);
    }

    for (int p = 0; p < P; ++p) {
        const int nbr = n - p * MB_P;
        const int nb = (nbr < MB_P) ? nbr : MB_P;
        #pragma unroll
        for (int it = 0; it < 4; ++it) {
            const int idx = it * 512 + t;
            const int si = idx >> 5, q = idx & 31;
            *(ushort4*)&zt[p & 1][si * ZPAD + q * 4] = pack4(zreg[it]);
        }
        __syncthreads();                     // vt (p==0) + zt[p&1] visible
        if (p + 1 < P) {                     // prefetch next pass into other buffer
            const int b2 = (p + 1) * MB_P;
            const int nb2r = n - b2;
            const int nb2 = (nb2r < MB_P) ? nb2r : MB_P;
            #pragma unroll
            for (int it = 0; it < 4; ++it) {
                const int idx = it * 512 + t;
                const int si = idx >> 5, q = idx & 31;
                zreg[it] = make_float4(0.f, 0.f, 0.f, 0.f);
                if (si < nb2)
                    zreg[it] = *(const float4*)&z[(size_t)lidx[b2 + si] * HIDDEN + kbase + q * 4];
            }
        }
        f32x4 acc0 = {0.f, 0.f, 0.f, 0.f}, acc1 = {0.f, 0.f, 0.f, 0.f};
        const ushort* zr0 = &zt[p & 1][(wm * 32 + m16) * ZPAD];
        const ushort* zr1 = zr0 + 16 * ZPAD;
        const ushort* vr  = &vt[(wr * 16 + m16) * VPAD];
        #pragma unroll
        for (int kt = 0; kt < 4; ++kt) {
            const int koff = kt * 32 + quad * 8;
            const bf16x8 bf = *(const bf16x8*)&vr[koff];
            const bf16x8 a0 = *(const bf16x8*)&zr0[koff];
            const bf16x8 a1 = *(const bf16x8*)&zr1[koff];
            acc0 = __builtin_amdgcn_mfma_f32_16x16x32_bf16(a0, bf, acc0, 0, 0, 0);
            acc1 = __builtin_amdgcn_mfma_f32_16x16x32_bf16(a1, bf, acc1, 0, 0, 0);
        }
        // C/D: col(=r)=lane&15, row(=si)=quad*4+reg ; fire-and-forget atomics
        const int r = wr * 16 + m16;
        const int base = p * MB_P;
        #pragma unroll
        for (int reg = 0; reg < 4; ++reg) {
            const int row = wm * 32 + quad * 4 + reg;
            if (row < nb)
                atomicAdd(&proj[(size_t)lidx[base + row] * RANK + r], acc0[reg]);
            if (row + 16 < nb)
                atomicAdd(&proj[(size_t)lidx[base + row + 16] * RANK + r], acc1[reg]);
        }
    }
}

// K2: out[b,h] = z[b,h] + sum_r proj[b,r] * u[l,h,r]   via MFMA bf16
// Same self-derived list. 512 threads: wave w -> h-tile (w&1, 64h),
// sample-group (w>>1, 32 samples). 128 samples/pass (P==1 almost always).
__global__ __launch_bounds__(512)
void k_delta(const float* __restrict__ z, const float* __restrict__ u,
             const int* __restrict__ ids, const float* __restrict__ proj,
             float* __restrict__ out)
{
    const int hc = blockIdx.x, l = blockIdx.y;
    const int t = threadIdx.x;
    const int w = t >> 6, lane = t & 63;
    const int m16 = lane & 15, quad = lane >> 4;
    const int wr = w & 1, wm = w >> 1;
    const int hbase = hc * HCH;

    __shared__ int    lidx[BATCH];           // 8 KB
    __shared__ int    nsh;
    __shared__ ushort ut[HCH * UPAD];        // 18 KB [h][r]
    __shared__ ushort pt[2][MB_D * PPAD];    // 36 KB [si][r] double-buffered

    if (t == 0) nsh = 0;

    // issue U loads first; they fly over the compaction
    float4 ureg[4];
    #pragma unroll
    for (int it = 0; it < 4; ++it) {
        const int idx = it * 512 + t;        // 2048 float4 = 128h x 16
        const int hh = idx >> 4, rq = idx & 15;
        ureg[it] = *(const float4*)&u[((size_t)l * HIDDEN + hbase + hh) * RANK + rq * 4];
    }
    __syncthreads();                         // nsh = 0 visible

    {
        const int4 iv = ((const int4*)ids)[t];
        if (iv.x == l) lidx[atomicAdd(&nsh, 1)] = t * 4 + 0;
        if (iv.y == l) lidx[atomicAdd(&nsh, 1)] = t * 4 + 1;
        if (iv.z == l) lidx[atomicAdd(&nsh, 1)] = t * 4 + 2;
        if (iv.w == l) lidx[atomicAdd(&nsh, 1)] = t * 4 + 3;
    }
    __syncthreads();                         // lidx, nsh final
    const int n = nsh;
    if (n == 0) return;

    const int P = (n + MB_D - 1) / MB_D;
    float4 preg[4];
    float  zep[2][4][4];
    {
        const int nb = (n < MB_D) ? n : MB_D;
        #pragma unroll
        for (int it = 0; it < 4; ++it) {     // 2048 float4 = 128si x 16
            const int idx = it * 512 + t;
            const int si = idx >> 4, rq = idx & 15;
            preg[it] = make_float4(0.f, 0.f, 0.f, 0.f);
            if (si < nb)
                preg[it] = *(const float4*)&proj[(size_t)lidx[si] * RANK + rq * 4];
        }
        #pragma unroll
        for (int mt = 0; mt < 2; ++mt)
            #pragma unroll
            for (int reg = 0; reg < 4; ++reg) {
                const int si = wm * 32 + mt * 16 + quad * 4 + reg;
                const size_t rowb = (si < nb) ? ((size_t)lidx[si] * HIDDEN + hbase) : 0;
                #pragma unroll
                for (int nt = 0; nt < 4; ++nt) {
                    const int h = (wr * 4 + nt) * 16 + m16;
                    zep[mt][nt][reg] = (si < nb) ? z[rowb + h] : 0.f;
                }
            }
    }
    // convert + write U tile while proj/z loads fly
    #pragma unroll
    for (int it = 0; it < 4; ++it) {
        const int idx = it * 512 + t;
        const int hh = idx >> 4, rq = idx & 15;
        *(ushort4*)&ut[hh * UPAD + rq * 4] = pack4(ureg[it]);
    }

    for (int p = 0; p < P; ++p) {
        const int nbr = n - p * MB_D;
        const int nb = (nbr < MB_D) ? nbr : MB_D;
        const int base = p * MB_D;
        #pragma unroll
        for (int it = 0; it < 4; ++it) {
            const int idx = it * 512 + t;
            const int si = idx >> 4, rq = idx & 15;
            *(ushort4*)&pt[p & 1][si * PPAD + rq * 4] = pack4(preg[it]);
        }
        __syncthreads();                     // ut (p==0) + pt[p&1] visible

        f32x4 acc[2][4];
        #pragma unroll
        for (int mt = 0; mt < 2; ++mt)
            #pragma unroll
            for (int nt = 0; nt < 4; ++nt)
                acc[mt][nt] = (f32x4){0.f, 0.f, 0.f, 0.f};

        const ushort* pr0 = &pt[p & 1][(wm * 32 + m16) * PPAD];
        const ushort* pr1 = pr0 + 16 * PPAD;
        #pragma unroll
        for (int kt = 0; kt < 2; ++kt) {
            const int koff = kt * 32 + quad * 8;
            const bf16x8 a0 = *(const bf16x8*)&pr0[koff];
            const bf16x8 a1 = *(const bf16x8*)&pr1[koff];
            #pragma unroll
            for (int nt = 0; nt < 4; ++nt) {
                const int h = (wr * 4 + nt) * 16 + m16;
                const bf16x8 bf = *(const bf16x8*)&ut[h * UPAD + koff];
                acc[0][nt] = __builtin_amdgcn_mfma_f32_16x16x32_bf16(a0, bf, acc[0][nt], 0, 0, 0);
                acc[1][nt] = __builtin_amdgcn_mfma_f32_16x16x32_bf16(a1, bf, acc[1][nt], 0, 0, 0);
            }
        }
        // epilogue: out = z + delta (z prefetched before the pass)
        #pragma unroll
        for (int mt = 0; mt < 2; ++mt)
            #pragma unroll
            for (int reg = 0; reg < 4; ++reg) {
                const int si = wm * 32 + mt * 16 + quad * 4 + reg;
                if (si < nb) {
                    const size_t rowb = (size_t)lidx[base + si] * HIDDEN + hbase;
                    #pragma unroll
                    for (int nt = 0; nt < 4; ++nt) {
                        const int h = (wr * 4 + nt) * 16 + m16;
                        out[rowb + h] = zep[mt][nt][reg] + acc[mt][nt][reg];
                    }
                }
            }
        // prefetch next pass (rare: only layers with n > 128)
        if (p + 1 < P) {
            const int b2 = (p + 1) * MB_D;
            const int nb2r = n - b2;
            const int nb2 = (nb2r < MB_D) ? nb2r : MB_D;
            #pragma unroll
            for (int it = 0; it < 4; ++it) {
                const int idx = it * 512 + t;
                const int si = idx >> 4, rq = idx & 15;
                preg[it] = make_float4(0.f, 0.f, 0.f, 0.f);
                if (si < nb2)
                    preg[it] = *(const float4*)&proj[(size_t)lidx[b2 + si] * RANK + rq * 4];
            }
            #pragma unroll
            for (int mt = 0; mt < 2; ++mt)
                #pragma unroll
                for (int reg = 0; reg < 4; ++reg) {
                    const int si = wm * 32 + mt * 16 + quad * 4 + reg;
                    const size_t rowb = (si < nb2) ? ((size_t)lidx[b2 + si] * HIDDEN + hbase) : 0;
                    #pragma unroll
                    for (int nt = 0; nt < 4; ++nt) {
                        const int h = (wr * 4 + nt) * 16 + m16;
                        zep[mt][nt][reg] = (si < nb2) ? z[rowb + h] : 0.f;
                    }
                }
        }
    }
}

extern "C" void kernel_launch(void* const* d_in, const int* in_sizes, int n_in,
                              void* d_out, int out_size, void* d_ws, size_t ws_size,
                              hipStream_t stream)
{
    const float* z   = (const float*)d_in[0];
    const int*   ids = (const int*)d_in[1];
    const float* u   = (const float*)d_in[2];
    const float* v   = (const float*)d_in[3];
    float* out = (float*)d_out;
    float* proj = (float*)d_ws;              // 512 KB, zeroed async below

    hipMemsetAsync(proj, 0, (size_t)BATCH * RANK * sizeof(float), stream);
    hipLaunchKernelGGL(k_proj, dim3(HIDDEN / KC, NUM_LAYERS), dim3(512), 0, stream,
                       z, v, ids, proj);
    hipLaunchKernelGGL(k_delta, dim3(HIDDEN / HCH, NUM_LAYERS), dim3(512), 0, stream,
                       z, u, ids, proj, out);
}